// Round 2
// baseline (1568.675 us; speedup 1.0000x reference)
//
#include <hip/hip_runtime.h>
#include <hip/hip_bf16.h>

// Problem constants (fixed by the reference)
#define B_ 8
#define NHID_ 512
#define L_ 2048
#define AL_ 4
#define NHEAD_ 8
#define HDIM_ 64
#define D_ 512            // NHEAD_*HDIM_
#define SCALE_ 0.125f     // 1/sqrt(64)

// ---------------------------------------------------------------------------
// Unified tiled fp32 GEMM:  C[z][n][m] = sum_k A[z][k][m] * W[k][n] + bias[n]
//   A: per-batch [K=512][M], M contiguous (pitch M), batch stride sAb
//   W: [512][512] row-major (k-major), N contiguous
//   C: per-batch [N=512][M], M contiguous (pitch M), batch stride sCb
// Tiles: BM=128, BN=128, BK=16; 256 threads; each thread 8(n) x 8(m)
// (split 4+4 across two 64-wide halves in each dim).
// Serves q/k/v projections, axial k/v projections, and the output projection
// (all have K=512, N=512, M-contiguous A and C, M a multiple of 128).
// ---------------------------------------------------------------------------
__global__ __launch_bounds__(256)
void gemm_tn(const float* __restrict__ A, const float* __restrict__ W,
             const float* __restrict__ bias, float* __restrict__ C,
             int M, long long sAb, long long sCb) {
  __shared__ float As[16][128];
  __shared__ float Ws[16][128];

  const int tid = threadIdx.x;
  const int bm = blockIdx.x * 128;
  const int bn = blockIdx.y * 128;
  const float* Ab = A + (size_t)blockIdx.z * sAb + bm;
  const float* Wb = W + bn;
  float* Cb = C + (size_t)blockIdx.z * sCb;

  const int tidm = tid & 15;    // 16 threads across m; owns m0..+3 and m0+64..+67
  const int tidn = tid >> 4;    // 16 threads across n; owns n0..+3 and n0+64..+67
  const int m0 = tidm * 4;
  const int n0 = tidn * 4;

  float acc[8][8];
#pragma unroll
  for (int i = 0; i < 8; i++)
#pragma unroll
    for (int j = 0; j < 8; j++) acc[i][j] = 0.f;

  // Staging: each 16x128 tile = 512 float4; thread t loads float4 #t and #t+256.
  const int r0 = tid >> 5, c0 = (tid & 31) << 2;        // rows 0..7
  const int r1 = (tid + 256) >> 5, c1 = c0;             // rows 8..15

  for (int k0 = 0; k0 < 512; k0 += 16) {
    float4 a0g = *(const float4*)&Ab[(size_t)(k0 + r0) * M + c0];
    float4 a1g = *(const float4*)&Ab[(size_t)(k0 + r1) * M + c1];
    float4 w0g = *(const float4*)&Wb[(size_t)(k0 + r0) * 512 + c0];
    float4 w1g = *(const float4*)&Wb[(size_t)(k0 + r1) * 512 + c1];
    *(float4*)&As[r0][c0] = a0g;
    *(float4*)&As[r1][c1] = a1g;
    *(float4*)&Ws[r0][c0] = w0g;
    *(float4*)&Ws[r1][c1] = w1g;
    __syncthreads();
#pragma unroll
    for (int kk = 0; kk < 16; kk++) {
      float4 av0 = *(const float4*)&As[kk][m0];
      float4 av1 = *(const float4*)&As[kk][m0 + 64];
      float4 wv0 = *(const float4*)&Ws[kk][n0];
      float4 wv1 = *(const float4*)&Ws[kk][n0 + 64];
      float am[8] = {av0.x, av0.y, av0.z, av0.w, av1.x, av1.y, av1.z, av1.w};
      float wn[8] = {wv0.x, wv0.y, wv0.z, wv0.w, wv1.x, wv1.y, wv1.z, wv1.w};
#pragma unroll
      for (int i = 0; i < 8; i++)
#pragma unroll
        for (int j = 0; j < 8; j++)
          acc[i][j] = fmaf(am[j], wn[i], acc[i][j]);
    }
    __syncthreads();
  }

#pragma unroll
  for (int i = 0; i < 8; i++) {
    const int n = bn + n0 + (i < 4 ? i : 60 + i);  // i>=4 -> n0+64+(i-4)
    const float bv = bias[n];
    float4 q0 = make_float4(acc[i][0] + bv, acc[i][1] + bv, acc[i][2] + bv, acc[i][3] + bv);
    float4 q1 = make_float4(acc[i][4] + bv, acc[i][5] + bv, acc[i][6] + bv, acc[i][7] + bv);
    *(float4*)&Cb[(size_t)n * M + bm + m0]      = q0;
    *(float4*)&Cb[(size_t)n * M + bm + m0 + 64] = q1;
  }
}

// ---------------------------------------------------------------------------
// Fused window attention per position l:
//   scores over {k[l-1],k[l],k[l+1], ak[a=0..3]} (zero-padded OOB entries keep
//   score 0 and still participate in softmax, matching the reference unfold),
//   softmax over the 7 entries, then att = sum alpha * {v window, av}.
// One thread per l; all loads coalesced across threads (contiguous in l).
// q/k/v/att: [B][512][L].  ak/av: [BCH][512][AL][L] (chunk-local batch bb).
// ---------------------------------------------------------------------------
__global__ __launch_bounds__(256)
void attn_win(const float* __restrict__ q, const float* __restrict__ k,
              const float* __restrict__ v, const float* __restrict__ ak,
              const float* __restrict__ av, float* __restrict__ att, int b0) {
  const int l  = blockIdx.x * 256 + threadIdx.x;
  const int bb = blockIdx.z / NHEAD_;   // chunk-local batch
  const int n  = blockIdx.z % NHEAD_;
  const int b  = b0 + bb;

  const size_t qoff = ((size_t)b * D_ + n * HDIM_) * L_ + l;
  const float* qp = q + qoff;
  const float* kp = k + qoff;
  const float* vp = v + qoff;
  float* ap = att + qoff;
  const size_t aoff = ((size_t)bb * D_ + n * HDIM_) * (size_t)AL_ * L_ + l;
  const float* akp = ak + aoff;
  const float* avp = av + aoff;

  const bool has_m = (l > 0);
  const bool has_p = (l < L_ - 1);

  float qr[HDIM_];
#pragma unroll
  for (int d = 0; d < HDIM_; d++) qr[d] = qp[(size_t)d * L_];

  float s0 = 0.f, s1 = 0.f, s2 = 0.f, s3 = 0.f, s4 = 0.f, s5 = 0.f, s6 = 0.f;
#pragma unroll
  for (int d = 0; d < HDIM_; d++) {
    const size_t o = (size_t)d * L_;
    float kc = kp[o];
    float km = has_m ? kp[o - 1] : 0.f;
    float kq = has_p ? kp[o + 1] : 0.f;
    s0 = fmaf(qr[d], km, s0);
    s1 = fmaf(qr[d], kc, s1);
    s2 = fmaf(qr[d], kq, s2);
    const float* a = akp + (size_t)d * AL_ * L_;
    s3 = fmaf(qr[d], a[0], s3);
    s4 = fmaf(qr[d], a[(size_t)L_], s4);
    s5 = fmaf(qr[d], a[2 * (size_t)L_], s5);
    s6 = fmaf(qr[d], a[3 * (size_t)L_], s6);
  }
  s0 *= SCALE_; s1 *= SCALE_; s2 *= SCALE_; s3 *= SCALE_;
  s4 *= SCALE_; s5 *= SCALE_; s6 *= SCALE_;

  float mx = fmaxf(fmaxf(fmaxf(s0, s1), fmaxf(s2, s3)), fmaxf(fmaxf(s4, s5), s6));
  float e0 = __expf(s0 - mx), e1 = __expf(s1 - mx), e2 = __expf(s2 - mx);
  float e3 = __expf(s3 - mx), e4 = __expf(s4 - mx), e5 = __expf(s5 - mx);
  float e6 = __expf(s6 - mx);
  float inv = 1.f / (e0 + e1 + e2 + e3 + e4 + e5 + e6);
  e0 *= inv; e1 *= inv; e2 *= inv; e3 *= inv; e4 *= inv; e5 *= inv; e6 *= inv;

#pragma unroll
  for (int d = 0; d < HDIM_; d++) {
    const size_t o = (size_t)d * L_;
    float vc = vp[o];
    float vm = has_m ? vp[o - 1] : 0.f;
    float vq = has_p ? vp[o + 1] : 0.f;
    const float* a = avp + (size_t)d * AL_ * L_;
    float r = e0 * vm + e1 * vc + e2 * vq;
    r = fmaf(e3, a[0], r);
    r = fmaf(e4, a[(size_t)L_], r);
    r = fmaf(e5, a[2 * (size_t)L_], r);
    r = fmaf(e6, a[3 * (size_t)L_], r);
    ap[o] = r;
  }
}

// ---------------------------------------------------------------------------
extern "C" void kernel_launch(void* const* d_in, const int* in_sizes, int n_in,
                              void* d_out, int out_size, void* d_ws, size_t ws_size,
                              hipStream_t stream) {
  const float* x  = (const float*)d_in[0];
  const float* ax = (const float*)d_in[1];
  const float* Wq = (const float*)d_in[2];
  const float* bq = (const float*)d_in[3];
  const float* Wk = (const float*)d_in[4];
  const float* bk = (const float*)d_in[5];
  const float* Wv = (const float*)d_in[6];
  const float* bv = (const float*)d_in[7];
  const float* Wo = (const float*)d_in[8];
  const float* bo = (const float*)d_in[9];
  float* out = (float*)d_out;

  float* ws = (float*)d_ws;
  const size_t qkv_elems = (size_t)B_ * D_ * L_;       // 8,388,608 floats (33.5 MB)
  float* q   = ws;
  float* k   = q + qkv_elems;
  float* v   = k + qkv_elems;
  float* att = v + qkv_elems;
  float* akb = att + qkv_elems;

  // Choose ak/av batch-chunk so the whole thing fits in ws_size.
  // needed = 4*qkv + 2*BCH*D_*AL_*L_ floats. Deterministic in ws_size.
  int BCH = 8;
  while (BCH > 1 &&
         (4 * qkv_elems + 2 * (size_t)BCH * D_ * AL_ * L_) * sizeof(float) > ws_size)
    BCH >>= 1;
  const size_t chunk_elems = (size_t)BCH * D_ * AL_ * L_;
  float* avb = akb + chunk_elems;

  const dim3 blk(256);
  const long long sX  = (long long)NHID_ * L_;        // x batch stride
  const long long sQ  = (long long)D_ * L_;           // q/k/v/att batch stride
  const long long sAX = (long long)NHID_ * AL_ * L_;  // ax batch stride
  const long long sAK = (long long)D_ * AL_ * L_;     // ak/av batch stride

  // q, k, v projections (M = L per batch)
  gemm_tn<<<dim3(L_ / 128, 4, B_), blk, 0, stream>>>(x, Wq, bq, q, L_, sX, sQ);
  gemm_tn<<<dim3(L_ / 128, 4, B_), blk, 0, stream>>>(x, Wk, bk, k, L_, sX, sQ);
  gemm_tn<<<dim3(L_ / 128, 4, B_), blk, 0, stream>>>(x, Wv, bv, v, L_, sX, sQ);

  // axial k/v projections + attention, chunked over batches
  for (int b0 = 0; b0 < B_; b0 += BCH) {
    const float* axb = ax + (size_t)b0 * sAX;
    gemm_tn<<<dim3(AL_ * L_ / 128, 4, BCH), blk, 0, stream>>>(axb, Wk, bk, akb,
                                                              AL_ * L_, sAX, sAK);
    gemm_tn<<<dim3(AL_ * L_ / 128, 4, BCH), blk, 0, stream>>>(axb, Wv, bv, avb,
                                                              AL_ * L_, sAX, sAK);
    attn_win<<<dim3(L_ / 256, 1, BCH * NHEAD_), blk, 0, stream>>>(q, k, v, akb, avb,
                                                                  att, b0);
  }

  // output projection -> d_out ([B][NHID][L][1] == [B][512][L] contiguous)
  gemm_tn<<<dim3(L_ / 128, 4, B_), blk, 0, stream>>>(att, Wo, bo, out, L_, sQ, sX);
}

// Round 4
// 650.978 us; speedup vs baseline: 2.4097x; 2.4097x over previous
//
#include <hip/hip_runtime.h>
#include <hip/hip_bf16.h>

// Problem constants (fixed by the reference)
#define B_ 8
#define NHID_ 512
#define L_ 2048
#define AL_ 4
#define NHEAD_ 8
#define HDIM_ 64
#define D_ 512
#define SCALE_ 0.125f

typedef unsigned short ushort_t;
typedef __attribute__((ext_vector_type(8))) short bf16x8;
typedef __attribute__((ext_vector_type(4))) float f32x4;

__device__ __forceinline__ float bf2f(ushort_t u) {
  union { unsigned i; float f; } x; x.i = ((unsigned)u) << 16; return x.f;
}
__device__ __forceinline__ ushort_t f2bf(float f) {   // round-to-nearest-even
  unsigned u = __float_as_uint(f);
  unsigned r = (u + 0x7FFFu + ((u >> 16) & 1u)) >> 16;
  return (ushort_t)r;
}
__device__ __forceinline__ void gload16(const ushort_t* g, ushort_t* l) {
  __builtin_amdgcn_global_load_lds(
      (const __attribute__((address_space(1))) unsigned int*)g,
      (__attribute__((address_space(3))) unsigned int*)l, 16, 0, 0);
}

// ---------------------------------------------------------------------------
// Tiled transpose + convert-to-bf16.  in[z][R][C] (Tin) -> out[z][C][R] (bf16)
// R, C multiples of 32. Block (32,8), each block does a 32x32 tile.
// ---------------------------------------------------------------------------
template <typename Tin>
__global__ __launch_bounds__(256)
void transpose_conv(const Tin* __restrict__ in, ushort_t* __restrict__ out,
                    int R, int C) {
  __shared__ float t[32][33];
  const size_t z = (size_t)blockIdx.z * R * C;
  const int cb = blockIdx.x * 32, rb = blockIdx.y * 32;
  const int tx = threadIdx.x, ty = threadIdx.y;
#pragma unroll
  for (int i = 0; i < 4; i++) {
    const int r = rb + ty + i * 8;
    float v;
    if constexpr (sizeof(Tin) == 4) v = ((const float*)in)[z + (size_t)r * C + cb + tx];
    else                            v = bf2f(((const ushort_t*)in)[z + (size_t)r * C + cb + tx]);
    t[ty + i * 8][tx] = v;
  }
  __syncthreads();
#pragma unroll
  for (int i = 0; i < 4; i++) {
    const int c = cb + ty + i * 8;
    out[z + (size_t)c * R + rb + tx] = f2bf(t[tx][ty + i * 8]);
  }
}

__global__ void prep_bias(const float* __restrict__ bq, const float* __restrict__ bk,
                          const float* __restrict__ bv, float* __restrict__ bcat) {
  const int i = blockIdx.x * 256 + threadIdx.x;  // 1536
  const float* s = i < 512 ? bq : (i < 1024 ? bk : bv);
  bcat[i] = s[i & 511];
}

// ---------------------------------------------------------------------------
// bf16 MFMA GEMM:  C[b][n][m] = sum_k A[(b,m)][k] * Wt[n][k] + bias[n]
//   A : [Mtot][512] bf16, k-contiguous rows (pre-transposed input)
//   Wt: [Ntot][512] bf16, k-contiguous rows (pre-transposed weights)
//   C : routed to C0/C1/C2 by n>>9; each buffer [b][512][Mb], m-contiguous.
// Tile 128x128, BK=32, 4 waves, 4x4 16x16x32 fragments per wave.
// global_load_lds(16B) staging, XOR chunk swizzle (c ^= (row>>1)&3):
// linear LDS dest + pre-swizzled global src + swizzled ds_read (rule #21);
// per-16-lane b128 reads touch all 32 banks twice (2-way = free, m136).
// ---------------------------------------------------------------------------
template <int OUTF>
__global__ __launch_bounds__(256)
void gemm_mfma(const ushort_t* __restrict__ A, const ushort_t* __restrict__ W,
               const float* __restrict__ bias, void* __restrict__ C0,
               void* __restrict__ C1, void* __restrict__ C2,
               int Ntiles, int MbShift) {
  __shared__ ushort_t lds[8192];  // 16 KB: A-tile elems [0,4096), W-tile [4096,8192)
  const int tid = threadIdx.x;
  const int l = tid & 63, w = tid >> 6;

  // bijective XCD swizzle (gridDim.x % 8 == 0 for all launches here)
  const int nwg = gridDim.x;
  const int id = (blockIdx.x & 7) * (nwg >> 3) + (blockIdx.x >> 3);
  const int nt = id % Ntiles, mt = id / Ntiles;
  const int bm = mt * 128, bn = nt * 128;

  // staging: thread handles chunks ci = j*256 + w*64 + l (16 B each), j=0..3
  const ushort_t* gsrc[4];
  ushort_t* ldst[4];
#pragma unroll
  for (int j = 0; j < 4; j++) {
    const int ci = j * 256 + w * 64 + l;
    const int row = (ci & 511) >> 2;
    const int cp = (ci & 3) ^ ((row >> 1) & 3);  // pre-swizzled source chunk
    gsrc[j] = (ci < 512 ? A + (size_t)(bm + row) * 512
                        : W + (size_t)(bn + row) * 512) + cp * 8;
    ldst[j] = &lds[j * 2048 + w * 512];  // wave-uniform dest; HW adds lane*16B
  }

  const int wm = (w & 1) * 64, wn = (w >> 1) * 64;
  int boff[4], aoff[4];
#pragma unroll
  for (int i = 0; i < 4; i++) {
    const int rb = wm + i * 16 + (l & 15);
    boff[i] = rb * 32 + (((l >> 4) ^ ((rb >> 1) & 3)) * 8);
    const int ra = wn + i * 16 + (l & 15);
    aoff[i] = 4096 + ra * 32 + (((l >> 4) ^ ((ra >> 1) & 3)) * 8);
  }

  f32x4 acc[4][4] = {};
  for (int kt = 0; kt < 16; kt++) {
    if (kt) __syncthreads();
#pragma unroll
    for (int j = 0; j < 4; j++) gload16(gsrc[j] + kt * 32, ldst[j]);
    __syncthreads();
    bf16x8 bf[4], af[4];
#pragma unroll
    for (int i = 0; i < 4; i++) bf[i] = *(const bf16x8*)&lds[boff[i]];
#pragma unroll
    for (int i = 0; i < 4; i++) af[i] = *(const bf16x8*)&lds[aoff[i]];
#pragma unroll
    for (int ni = 0; ni < 4; ni++)
#pragma unroll
      for (int mi = 0; mi < 4; mi++)
        acc[ni][mi] = __builtin_amdgcn_mfma_f32_16x16x32_bf16(af[ni], bf[mi],
                                                              acc[ni][mi], 0, 0, 0);
  }

  // epilogue: D lane map col(m)=l&15, row(n)=(l>>4)*4+r  [m89-verified]
  const int bufi = bn >> 9;
  void* Cb = bufi == 0 ? C0 : (bufi == 1 ? C1 : C2);
  const int nb = bn & 511;
  const int Mb = 1 << MbShift;
#pragma unroll
  for (int ni = 0; ni < 4; ni++) {
#pragma unroll
    for (int r = 0; r < 4; r++) {
      const int tn = wn + ni * 16 + (l >> 4) * 4 + r;
      const float bv = bias[bn + tn];
      const int nl = nb + tn;
#pragma unroll
      for (int mi = 0; mi < 4; mi++) {
        const int m = bm + wm + mi * 16 + (l & 15);
        const int b = m >> MbShift, ml = m & (Mb - 1);
        const size_t idx = (((size_t)b * 512 + nl) << MbShift) + ml;
        const float val = acc[ni][mi][r] + bv;
        if (OUTF) ((float*)Cb)[idx] = val;
        else      ((ushort_t*)Cb)[idx] = f2bf(val);
      }
    }
  }
}

// ---------------------------------------------------------------------------
// Fused window attention (bf16 in/out, fp32 math). One thread per l.
// q/k/v/att: [B][512][L] bf16 (global batch b).
// ak/av: [BCH][512][AL*L] bf16 (chunk-local batch bb).
// Zero-padded OOB window entries keep score 0 and participate in softmax
// (matches reference unfold semantics; verified against ref in R2 baseline).
// ---------------------------------------------------------------------------
__global__ __launch_bounds__(256)
void attn_win(const ushort_t* __restrict__ q, const ushort_t* __restrict__ k,
              const ushort_t* __restrict__ v, const ushort_t* __restrict__ ak,
              const ushort_t* __restrict__ av, ushort_t* __restrict__ att,
              int b0) {
  const int l = blockIdx.x * 256 + threadIdx.x;
  const int bb = blockIdx.z >> 3;   // chunk-local batch
  const int n = blockIdx.z & 7;
  const int b = b0 + bb;

  const size_t qoff = ((size_t)b * D_ + n * HDIM_) * L_ + l;
  const ushort_t* qp = q + qoff;
  const ushort_t* kp = k + qoff;
  const ushort_t* vp = v + qoff;
  ushort_t* ap = att + qoff;
  const size_t aoff = ((size_t)bb * D_ + n * HDIM_) * (size_t)(AL_ * L_) + l;
  const ushort_t* akp = ak + aoff;
  const ushort_t* avp = av + aoff;

  const bool has_m = (l > 0);
  const bool has_p = (l < L_ - 1);

  float qr[HDIM_];
#pragma unroll
  for (int d = 0; d < HDIM_; d++) qr[d] = bf2f(qp[(size_t)d * L_]);

  float s0 = 0.f, s1 = 0.f, s2 = 0.f, s3 = 0.f, s4 = 0.f, s5 = 0.f, s6 = 0.f;
#pragma unroll
  for (int d = 0; d < HDIM_; d++) {
    const size_t o = (size_t)d * L_;
    const float kc = bf2f(kp[o]);
    const float km = has_m ? bf2f(kp[o - 1]) : 0.f;
    const float kq = has_p ? bf2f(kp[o + 1]) : 0.f;
    s0 = fmaf(qr[d], km, s0);
    s1 = fmaf(qr[d], kc, s1);
    s2 = fmaf(qr[d], kq, s2);
    const ushort_t* a = akp + (size_t)d * AL_ * L_;
    s3 = fmaf(qr[d], bf2f(a[0]), s3);
    s4 = fmaf(qr[d], bf2f(a[(size_t)L_]), s4);
    s5 = fmaf(qr[d], bf2f(a[2 * (size_t)L_]), s5);
    s6 = fmaf(qr[d], bf2f(a[3 * (size_t)L_]), s6);
  }
  s0 *= SCALE_; s1 *= SCALE_; s2 *= SCALE_; s3 *= SCALE_;
  s4 *= SCALE_; s5 *= SCALE_; s6 *= SCALE_;

  const float mx = fmaxf(fmaxf(fmaxf(s0, s1), fmaxf(s2, s3)),
                         fmaxf(fmaxf(s4, s5), s6));
  float e0 = __expf(s0 - mx), e1 = __expf(s1 - mx), e2 = __expf(s2 - mx);
  float e3 = __expf(s3 - mx), e4 = __expf(s4 - mx), e5 = __expf(s5 - mx);
  float e6 = __expf(s6 - mx);
  const float inv = 1.f / (e0 + e1 + e2 + e3 + e4 + e5 + e6);
  e0 *= inv; e1 *= inv; e2 *= inv; e3 *= inv; e4 *= inv; e5 *= inv; e6 *= inv;

#pragma unroll
  for (int d = 0; d < HDIM_; d++) {
    const size_t o = (size_t)d * L_;
    const float vc = bf2f(vp[o]);
    const float vm = has_m ? bf2f(vp[o - 1]) : 0.f;
    const float vq = has_p ? bf2f(vp[o + 1]) : 0.f;
    const ushort_t* a = avp + (size_t)d * AL_ * L_;
    float r = e0 * vm + e1 * vc + e2 * vq;
    r = fmaf(e3, bf2f(a[0]), r);
    r = fmaf(e4, bf2f(a[(size_t)L_]), r);
    r = fmaf(e5, bf2f(a[2 * (size_t)L_]), r);
    r = fmaf(e6, bf2f(a[3 * (size_t)L_]), r);
    ap[o] = f2bf(r);
  }
}

// ---------------------------------------------------------------------------
extern "C" void kernel_launch(void* const* d_in, const int* in_sizes, int n_in,
                              void* d_out, int out_size, void* d_ws, size_t ws_size,
                              hipStream_t stream) {
  const float* x  = (const float*)d_in[0];
  const float* ax = (const float*)d_in[1];
  const float* Wq = (const float*)d_in[2];
  const float* bq = (const float*)d_in[3];
  const float* Wk = (const float*)d_in[4];
  const float* bk = (const float*)d_in[5];
  const float* Wv = (const float*)d_in[6];
  const float* bv = (const float*)d_in[7];
  const float* Wo = (const float*)d_in[8];
  const float* bo = (const float*)d_in[9];
  float* out = (float*)d_out;

  // ---- workspace layout (bf16 elems), with deterministic batch-chunking ----
  const size_t E  = (size_t)B_ * D_ * L_;         // 8,388,608
  const size_t EA = (size_t)B_ * D_ * AL_ * L_;   // 33,554,432
  const size_t CH1 = (size_t)D_ * AL_ * L_;       // per-batch ak/av elems
  const size_t wfix = 1536 * 512 + 512 * 512 + 3072;  // weights + bias

  // choose BCH so (4E + EA + 2*BCH*CH1 + wfix)*2 bytes <= ws_size
  int BCH = 8;
  while (BCH > 1 &&
         (4 * E + EA + 2 * (size_t)BCH * CH1 + wfix) * 2 > ws_size)
    BCH >>= 1;
  const size_t chunkE = (size_t)BCH * CH1;

  ushort_t* wsu = (ushort_t*)d_ws;
  ushort_t* xTb   = wsu;              // [B*L][512]   (reused as attb after qkv)
  ushort_t* qb    = xTb + E;          // [B][512][L]
  ushort_t* kb    = qb + E;
  ushort_t* vb    = kb + E;
  ushort_t* axTb  = vb + E;           // [B*AL*L][512] (reused as attTb at end)
  ushort_t* akb   = axTb + EA;        // [BCH][512][AL*L]
  ushort_t* avb   = akb + chunkE;
  ushort_t* WcatT = avb + chunkE;     // [1536][512]
  ushort_t* WoT   = WcatT + 1536 * 512;
  float*    bcat  = (float*)(WoT + 512 * 512);  // [1536]
  ushort_t* attb  = xTb;              // [B][512][L]   (xTb dead after qkv GEMM)
  ushort_t* attTb = axTb;             // [B*L][512]    (axTb dead after last akav GEMM)

  const dim3 t32x8(32, 8);

  // --- weight prep: Wt[n][k] = W[k][n], bf16 ---
  transpose_conv<float><<<dim3(16, 16, 1), t32x8, 0, stream>>>(Wq, WcatT, 512, 512);
  transpose_conv<float><<<dim3(16, 16, 1), t32x8, 0, stream>>>(Wk, WcatT + 512 * 512, 512, 512);
  transpose_conv<float><<<dim3(16, 16, 1), t32x8, 0, stream>>>(Wv, WcatT + 1024 * 512, 512, 512);
  transpose_conv<float><<<dim3(16, 16, 1), t32x8, 0, stream>>>(Wo, WoT, 512, 512);
  prep_bias<<<dim3(6), dim3(256), 0, stream>>>(bq, bk, bv, bcat);

  // --- x -> xTb [B*L][512] ---
  transpose_conv<float><<<dim3(64, 16, B_), t32x8, 0, stream>>>(x, xTb, 512, L_);

  // --- ax -> axTb [B*AL*L][512] (whole tensor, read per-chunk below) ---
  transpose_conv<float><<<dim3(256, 16, B_), t32x8, 0, stream>>>(ax, axTb, 512, AL_ * L_);

  // --- fused q/k/v GEMM: M=16384, N=1536 -> qb,kb,vb ---
  gemm_mfma<0><<<dim3(128 * 12), dim3(256), 0, stream>>>(
      xTb, WcatT, bcat, qb, kb, vb, 12, 11);

  // --- ak/av GEMM + attention, chunked over batches (ws-size safe) ---
  for (int b0 = 0; b0 < B_; b0 += BCH) {
    const ushort_t* axc = axTb + (size_t)b0 * CH1;   // CH1 = AL*L rows * 512
    gemm_mfma<0><<<dim3(BCH * 64 * 8), dim3(256), 0, stream>>>(
        axc, WcatT + 512 * 512, bcat + 512, akb, avb, nullptr, 8, 13);
    attn_win<<<dim3(L_ / 256, 1, BCH * NHEAD_), dim3(256), 0, stream>>>(
        qb, kb, vb, akb, avb, attb, b0);
  }

  // --- att -> attTb [B*L][512] (overwrites axTb; safe: all readers done) ---
  transpose_conv<ushort_t><<<dim3(64, 16, B_), t32x8, 0, stream>>>(attb, attTb, 512, L_);

  // --- output projection: M=16384, N=512, fp32 out -> d_out [B][512][L] ---
  gemm_mfma<1><<<dim3(128 * 4), dim3(256), 0, stream>>>(
      attTb, WoT, bo, out, nullptr, nullptr, 4, 11);
}

// Round 5
// 498.419 us; speedup vs baseline: 3.1473x; 1.3061x over previous
//
#include <hip/hip_runtime.h>
#include <hip/hip_bf16.h>

// Problem constants (fixed by the reference)
#define B_ 8
#define NHID_ 512
#define L_ 2048
#define AL_ 4
#define NHEAD_ 8
#define HDIM_ 64
#define D_ 512
#define SCALE_ 0.125f

typedef unsigned short ushort_t;
typedef __attribute__((ext_vector_type(8))) short bf16x8;
typedef __attribute__((ext_vector_type(8))) unsigned short u16x8;
typedef __attribute__((ext_vector_type(4))) float f32x4;

__device__ __forceinline__ float bf2f(ushort_t u) {
  union { unsigned i; float f; } x; x.i = ((unsigned)u) << 16; return x.f;
}
__device__ __forceinline__ ushort_t f2bf(float f) {   // round-to-nearest-even
  unsigned u = __float_as_uint(f);
  unsigned r = (u + 0x7FFFu + ((u >> 16) & 1u)) >> 16;
  return (ushort_t)r;
}
__device__ __forceinline__ void gload16(const ushort_t* g, ushort_t* l) {
  __builtin_amdgcn_global_load_lds(
      (const __attribute__((address_space(1))) unsigned int*)g,
      (__attribute__((address_space(3))) unsigned int*)l, 16, 0, 0);
}

// ---------------------------------------------------------------------------
// Tiled transpose + convert-to-bf16.  in[z][R][C] (Tin) -> out[z][C][R] (bf16)
// ---------------------------------------------------------------------------
template <typename Tin>
__global__ __launch_bounds__(256)
void transpose_conv(const Tin* __restrict__ in, ushort_t* __restrict__ out,
                    int R, int C) {
  __shared__ float t[32][33];
  const size_t z = (size_t)blockIdx.z * R * C;
  const int cb = blockIdx.x * 32, rb = blockIdx.y * 32;
  const int tx = threadIdx.x, ty = threadIdx.y;
#pragma unroll
  for (int i = 0; i < 4; i++) {
    const int r = rb + ty + i * 8;
    float v;
    if constexpr (sizeof(Tin) == 4) v = ((const float*)in)[z + (size_t)r * C + cb + tx];
    else                            v = bf2f(((const ushort_t*)in)[z + (size_t)r * C + cb + tx]);
    t[ty + i * 8][tx] = v;
  }
  __syncthreads();
#pragma unroll
  for (int i = 0; i < 4; i++) {
    const int c = cb + ty + i * 8;
    out[z + (size_t)c * R + rb + tx] = f2bf(t[tx][ty + i * 8]);
  }
}

__global__ void prep_bias(const float* __restrict__ bq, const float* __restrict__ bk,
                          const float* __restrict__ bv, float* __restrict__ bcat) {
  const int i = blockIdx.x * 256 + threadIdx.x;  // 1536
  const float* s = i < 512 ? bq : (i < 1024 ? bk : bv);
  bcat[i] = s[i & 511];
}

// ---------------------------------------------------------------------------
// bf16 MFMA GEMM (unchanged from R4 — verified passing).
// ---------------------------------------------------------------------------
template <int OUTF>
__global__ __launch_bounds__(256)
void gemm_mfma(const ushort_t* __restrict__ A, const ushort_t* __restrict__ W,
               const float* __restrict__ bias, void* __restrict__ C0,
               void* __restrict__ C1, void* __restrict__ C2,
               int Ntiles, int MbShift) {
  __shared__ ushort_t lds[8192];
  const int tid = threadIdx.x;
  const int l = tid & 63, w = tid >> 6;

  const int nwg = gridDim.x;
  const int id = (blockIdx.x & 7) * (nwg >> 3) + (blockIdx.x >> 3);
  const int nt = id % Ntiles, mt = id / Ntiles;
  const int bm = mt * 128, bn = nt * 128;

  const ushort_t* gsrc[4];
  ushort_t* ldst[4];
#pragma unroll
  for (int j = 0; j < 4; j++) {
    const int ci = j * 256 + w * 64 + l;
    const int row = (ci & 511) >> 2;
    const int cp = (ci & 3) ^ ((row >> 1) & 3);
    gsrc[j] = (ci < 512 ? A + (size_t)(bm + row) * 512
                        : W + (size_t)(bn + row) * 512) + cp * 8;
    ldst[j] = &lds[j * 2048 + w * 512];
  }

  const int wm = (w & 1) * 64, wn = (w >> 1) * 64;
  int boff[4], aoff[4];
#pragma unroll
  for (int i = 0; i < 4; i++) {
    const int rb = wm + i * 16 + (l & 15);
    boff[i] = rb * 32 + (((l >> 4) ^ ((rb >> 1) & 3)) * 8);
    const int ra = wn + i * 16 + (l & 15);
    aoff[i] = 4096 + ra * 32 + (((l >> 4) ^ ((ra >> 1) & 3)) * 8);
  }

  f32x4 acc[4][4] = {};
  for (int kt = 0; kt < 16; kt++) {
    if (kt) __syncthreads();
#pragma unroll
    for (int j = 0; j < 4; j++) gload16(gsrc[j] + kt * 32, ldst[j]);
    __syncthreads();
    bf16x8 bf[4], af[4];
#pragma unroll
    for (int i = 0; i < 4; i++) bf[i] = *(const bf16x8*)&lds[boff[i]];
#pragma unroll
    for (int i = 0; i < 4; i++) af[i] = *(const bf16x8*)&lds[aoff[i]];
#pragma unroll
    for (int ni = 0; ni < 4; ni++)
#pragma unroll
      for (int mi = 0; mi < 4; mi++)
        acc[ni][mi] = __builtin_amdgcn_mfma_f32_16x16x32_bf16(af[ni], bf[mi],
                                                              acc[ni][mi], 0, 0, 0);
  }

  const int bufi = bn >> 9;
  void* Cb = bufi == 0 ? C0 : (bufi == 1 ? C1 : C2);
  const int nb = bn & 511;
  const int Mb = 1 << MbShift;
#pragma unroll
  for (int ni = 0; ni < 4; ni++) {
#pragma unroll
    for (int r = 0; r < 4; r++) {
      const int tn = wn + ni * 16 + (l >> 4) * 4 + r;
      const float bv = bias[bn + tn];
      const int nl = nb + tn;
#pragma unroll
      for (int mi = 0; mi < 4; mi++) {
        const int m = bm + wm + mi * 16 + (l & 15);
        const int b = m >> MbShift, ml = m & (Mb - 1);
        const size_t idx = (((size_t)b * 512 + nl) << MbShift) + ml;
        const float val = acc[ni][mi][r] + bv;
        if (OUTF) ((float*)Cb)[idx] = val;
        else      ((ushort_t*)Cb)[idx] = f2bf(val);
      }
    }
  }
}

// ---------------------------------------------------------------------------
// Fused window attention v2. Layouts as before:
//   q/k/v/att: [B][512][L] bf16 (global b);  ak/av: [BCH][512][AL*L] (local bb).
// Work split: lane = lc*4+dc. Thread owns 8 l-positions (l8..l8+7, ushort8
// 16B loads) x 16 d's (d0=dc*16). Partial scores s[7][8] reduced across the
// 4 dc-lanes via shfl_xor(1,2); softmax computed redundantly per lane.
// Window neighbors via register shift + shfl(4); block-edge lanes patch with
// masked scalar loads (OOB -> 0, participates in softmax: reference semantics).
// No LDS, no barriers. VGPR target ~130 (was 256), 8x fewer mem instructions.
// ---------------------------------------------------------------------------
__global__ __launch_bounds__(256)
void attn_win(const ushort_t* __restrict__ q, const ushort_t* __restrict__ k,
              const ushort_t* __restrict__ v, const ushort_t* __restrict__ ak,
              const ushort_t* __restrict__ av, ushort_t* __restrict__ att,
              int b0) {
  const int lane = threadIdx.x & 63;
  const int w    = threadIdx.x >> 6;
  const int dc   = lane & 3;
  const int lc   = lane >> 2;
  const int bb = blockIdx.y >> 3, n = blockIdx.y & 7;
  const int b = b0 + bb;
  const int l8 = blockIdx.x * 512 + w * 128 + lc * 8;
  const int d0 = dc * 16;

  const size_t rq = ((size_t)b * D_ + n * HDIM_ + d0) * L_ + l8;
  const size_t ra = ((size_t)bb * D_ + n * HDIM_ + d0) * (size_t)(AL_ * L_) + l8;
  const ushort_t* qp = q + rq;
  const ushort_t* kp = k + rq;
  const ushort_t* vp = v + rq;
  ushort_t*       op = att + rq;
  const ushort_t* akp = ak + ra;
  const ushort_t* avp = av + ra;

  float s0[8] = {}, s1[8] = {}, s2[8] = {}, s3[8] = {};
  float s4[8] = {}, s5[8] = {}, s6[8] = {};

#pragma unroll 4
  for (int i = 0; i < 16; ++i) {
    const ushort_t* kr = kp + (size_t)i * L_;
    const ushort_t* ar = akp + (size_t)i * (AL_ * L_);
    const u16x8 qv = *(const u16x8*)(qp + (size_t)i * L_);
    const u16x8 kv = *(const u16x8*)kr;
    const u16x8 a0 = *(const u16x8*)(ar);
    const u16x8 a1 = *(const u16x8*)(ar + L_);
    const u16x8 a2 = *(const u16x8*)(ar + 2 * L_);
    const u16x8 a3 = *(const u16x8*)(ar + 3 * L_);
    float qf[8], kf[8];
#pragma unroll
    for (int j = 0; j < 8; ++j) { qf[j] = bf2f(qv[j]); kf[j] = bf2f(kv[j]); }
    float kl = __shfl_up(kf[7], 4);
    if (lc == 0) kl = (l8 > 0) ? bf2f(kr[-1]) : 0.f;
    float kh = __shfl_down(kf[0], 4);
    if (lc == 15) kh = (l8 + 8 < L_) ? bf2f(kr[8]) : 0.f;
#pragma unroll
    for (int j = 0; j < 8; ++j) {
      s0[j] = fmaf(qf[j], j ? kf[j - 1] : kl, s0[j]);
      s1[j] = fmaf(qf[j], kf[j], s1[j]);
      s2[j] = fmaf(qf[j], j < 7 ? kf[j + 1] : kh, s2[j]);
      s3[j] = fmaf(qf[j], bf2f(a0[j]), s3[j]);
      s4[j] = fmaf(qf[j], bf2f(a1[j]), s4[j]);
      s5[j] = fmaf(qf[j], bf2f(a2[j]), s5[j]);
      s6[j] = fmaf(qf[j], bf2f(a3[j]), s6[j]);
    }
  }

  // reduce partial scores across the 4 dc-lanes (lane bits 0-1)
#pragma unroll
  for (int j = 0; j < 8; ++j) {
    s0[j] += __shfl_xor(s0[j], 1); s0[j] += __shfl_xor(s0[j], 2);
    s1[j] += __shfl_xor(s1[j], 1); s1[j] += __shfl_xor(s1[j], 2);
    s2[j] += __shfl_xor(s2[j], 1); s2[j] += __shfl_xor(s2[j], 2);
    s3[j] += __shfl_xor(s3[j], 1); s3[j] += __shfl_xor(s3[j], 2);
    s4[j] += __shfl_xor(s4[j], 1); s4[j] += __shfl_xor(s4[j], 2);
    s5[j] += __shfl_xor(s5[j], 1); s5[j] += __shfl_xor(s5[j], 2);
    s6[j] += __shfl_xor(s6[j], 1); s6[j] += __shfl_xor(s6[j], 2);
  }

  // softmax over the 7 window entries, per l-position (redundant across dc)
#pragma unroll
  for (int j = 0; j < 8; ++j) {
    const float t0 = s0[j] * SCALE_, t1 = s1[j] * SCALE_, t2 = s2[j] * SCALE_;
    const float t3 = s3[j] * SCALE_, t4 = s4[j] * SCALE_, t5 = s5[j] * SCALE_;
    const float t6 = s6[j] * SCALE_;
    const float mx = fmaxf(fmaxf(fmaxf(t0, t1), fmaxf(t2, t3)),
                           fmaxf(fmaxf(t4, t5), t6));
    float e0 = __expf(t0 - mx), e1 = __expf(t1 - mx), e2 = __expf(t2 - mx);
    float e3 = __expf(t3 - mx), e4 = __expf(t4 - mx), e5 = __expf(t5 - mx);
    float e6 = __expf(t6 - mx);
    const float inv = 1.f / (e0 + e1 + e2 + e3 + e4 + e5 + e6);
    s0[j] = e0 * inv; s1[j] = e1 * inv; s2[j] = e2 * inv; s3[j] = e3 * inv;
    s4[j] = e4 * inv; s5[j] = e5 * inv; s6[j] = e6 * inv;
  }

  // output: att[d][l] = sum_w alpha_w * v_w[d][l]
#pragma unroll 4
  for (int i = 0; i < 16; ++i) {
    const ushort_t* vr = vp + (size_t)i * L_;
    const ushort_t* ar = avp + (size_t)i * (AL_ * L_);
    const u16x8 vv = *(const u16x8*)vr;
    const u16x8 a0 = *(const u16x8*)(ar);
    const u16x8 a1 = *(const u16x8*)(ar + L_);
    const u16x8 a2 = *(const u16x8*)(ar + 2 * L_);
    const u16x8 a3 = *(const u16x8*)(ar + 3 * L_);
    float vf[8];
#pragma unroll
    for (int j = 0; j < 8; ++j) vf[j] = bf2f(vv[j]);
    float vl = __shfl_up(vf[7], 4);
    if (lc == 0) vl = (l8 > 0) ? bf2f(vr[-1]) : 0.f;
    float vh = __shfl_down(vf[0], 4);
    if (lc == 15) vh = (l8 + 8 < L_) ? bf2f(vr[8]) : 0.f;
    u16x8 o;
#pragma unroll
    for (int j = 0; j < 8; ++j) {
      float r = s0[j] * (j ? vf[j - 1] : vl)
              + s1[j] * vf[j]
              + s2[j] * (j < 7 ? vf[j + 1] : vh);
      r = fmaf(s3[j], bf2f(a0[j]), r);
      r = fmaf(s4[j], bf2f(a1[j]), r);
      r = fmaf(s5[j], bf2f(a2[j]), r);
      r = fmaf(s6[j], bf2f(a3[j]), r);
      o[j] = f2bf(r);
    }
    *(u16x8*)(op + (size_t)i * L_) = o;
  }
}

// ---------------------------------------------------------------------------
extern "C" void kernel_launch(void* const* d_in, const int* in_sizes, int n_in,
                              void* d_out, int out_size, void* d_ws, size_t ws_size,
                              hipStream_t stream) {
  const float* x  = (const float*)d_in[0];
  const float* ax = (const float*)d_in[1];
  const float* Wq = (const float*)d_in[2];
  const float* bq = (const float*)d_in[3];
  const float* Wk = (const float*)d_in[4];
  const float* bk = (const float*)d_in[5];
  const float* Wv = (const float*)d_in[6];
  const float* bv = (const float*)d_in[7];
  const float* Wo = (const float*)d_in[8];
  const float* bo = (const float*)d_in[9];
  float* out = (float*)d_out;

  // ---- workspace layout (bf16 elems), deterministic batch-chunking ----
  const size_t E  = (size_t)B_ * D_ * L_;
  const size_t EA = (size_t)B_ * D_ * AL_ * L_;
  const size_t CH1 = (size_t)D_ * AL_ * L_;
  const size_t wfix = 1536 * 512 + 512 * 512 + 3072;

  int BCH = 8;
  while (BCH > 1 &&
         (4 * E + EA + 2 * (size_t)BCH * CH1 + wfix) * 2 > ws_size)
    BCH >>= 1;
  const size_t chunkE = (size_t)BCH * CH1;

  ushort_t* wsu = (ushort_t*)d_ws;
  ushort_t* xTb   = wsu;
  ushort_t* qb    = xTb + E;
  ushort_t* kb    = qb + E;
  ushort_t* vb    = kb + E;
  ushort_t* axTb  = vb + E;
  ushort_t* akb   = axTb + EA;
  ushort_t* avb   = akb + chunkE;
  ushort_t* WcatT = avb + chunkE;
  ushort_t* WoT   = WcatT + 1536 * 512;
  float*    bcat  = (float*)(WoT + 512 * 512);
  ushort_t* attb  = xTb;              // xTb dead after qkv GEMM
  ushort_t* attTb = axTb;             // axTb dead after last akav GEMM

  const dim3 t32x8(32, 8);

  transpose_conv<float><<<dim3(16, 16, 1), t32x8, 0, stream>>>(Wq, WcatT, 512, 512);
  transpose_conv<float><<<dim3(16, 16, 1), t32x8, 0, stream>>>(Wk, WcatT + 512 * 512, 512, 512);
  transpose_conv<float><<<dim3(16, 16, 1), t32x8, 0, stream>>>(Wv, WcatT + 1024 * 512, 512, 512);
  transpose_conv<float><<<dim3(16, 16, 1), t32x8, 0, stream>>>(Wo, WoT, 512, 512);
  prep_bias<<<dim3(6), dim3(256), 0, stream>>>(bq, bk, bv, bcat);

  transpose_conv<float><<<dim3(64, 16, B_), t32x8, 0, stream>>>(x, xTb, 512, L_);
  transpose_conv<float><<<dim3(256, 16, B_), t32x8, 0, stream>>>(ax, axTb, 512, AL_ * L_);

  gemm_mfma<0><<<dim3(128 * 12), dim3(256), 0, stream>>>(
      xTb, WcatT, bcat, qb, kb, vb, 12, 11);

  for (int b0 = 0; b0 < B_; b0 += BCH) {
    const ushort_t* axc = axTb + (size_t)b0 * CH1;
    gemm_mfma<0><<<dim3(BCH * 64 * 8), dim3(256), 0, stream>>>(
        axc, WcatT + 512 * 512, bcat + 512, akb, avb, nullptr, 8, 13);
    attn_win<<<dim3(L_ / 512, BCH * NHEAD_), dim3(256), 0, stream>>>(
        qb, kb, vb, akb, avb, attb, b0);
  }

  transpose_conv<ushort_t><<<dim3(64, 16, B_), t32x8, 0, stream>>>(attb, attTb, 512, L_);

  gemm_mfma<1><<<dim3(128 * 4), dim3(256), 0, stream>>>(
      attTb, WoT, bo, out, nullptr, nullptr, 4, 11);
}